// Round 4
// baseline (4182.074 us; speedup 1.0000x reference)
//
#include <hip/hip_runtime.h>

typedef unsigned short u16;
typedef __attribute__((ext_vector_type(8))) short short8;
typedef __attribute__((ext_vector_type(4))) short short4_t;
typedef __attribute__((ext_vector_type(4))) float float4_t;

#define B_ 4
#define LT_ 2048
#define LE_ 1024
#define D_ 1024
#define H_ 16
#define HD_ 64
#define NB_ 16
#define BS_ 128
#define M_ 4096
#define SCALE_ 0.125f

__device__ __forceinline__ float b2f(u16 u) {
  union { unsigned int i; float f; } v; v.i = ((unsigned int)u) << 16; return v.f;
}
__device__ __forceinline__ u16 f2b(float f) {
  union { float f; unsigned int i; } v; v.f = f;
  unsigned int x = v.i;
  return (u16)((x + 0x7fffu + ((x >> 16) & 1u)) >> 16);
}
__device__ __forceinline__ float gelu_f(float u) {
  float t = 0.7978845608028654f * (u + 0.044715f * u * u * u);
  return 0.5f * u * (1.f + tanhf(t));
}
__device__ __forceinline__ void store_val(u16* p, float x) { *p = f2b(x); }
__device__ __forceinline__ void store_val(float* p, float x) { *p = x; }

// ---------------- fp32 -> bf16 convert ----------------
__global__ __launch_bounds__(256)
void conv_k(const float* __restrict__ in, u16* __restrict__ out) {
  int i = (blockIdx.x * 256 + threadIdx.x) * 4;
  float4_t v = *(const float4_t*)(in + i);
  short4_t o;
  o[0] = (short)f2b(v[0]); o[1] = (short)f2b(v[1]);
  o[2] = (short)f2b(v[2]); o[3] = (short)f2b(v[3]);
  *(short4_t*)(out + i) = o;
}

// ---------------- transpose fp32 [R,Csub] (row stride) -> bf16 [Csub,R] ----------------
__global__ __launch_bounds__(256)
void transpose_k(const float* __restrict__ in, u16* __restrict__ out, int R, int rstride) {
  __shared__ u16 tile[32][33];
  int bx = blockIdx.x * 32, by = blockIdx.y * 32;
  int tx = threadIdx.x & 31, ty = threadIdx.x >> 5;
  #pragma unroll
  for (int y = ty; y < 32; y += 8)
    tile[y][tx] = f2b(in[(size_t)(by + y) * rstride + bx + tx]);
  __syncthreads();
  #pragma unroll
  for (int y = ty; y < 32; y += 8)
    out[(size_t)(bx + y) * R + by + tx] = tile[tx][y];
}

// ---------------- layernorm (rows of 1024): fp32 in -> bf16 out ----------------
__global__ __launch_bounds__(256)
void ln_k(const float* __restrict__ x, const float* __restrict__ sw,
          const float* __restrict__ bw, u16* __restrict__ out) {
  int row = blockIdx.x, tid = threadIdx.x;
  const float* xr = x + (size_t)row * 1024 + tid * 4;
  float4_t raw = *(const float4_t*)xr;
  float v0 = raw[0], v1 = raw[1], v2 = raw[2], v3 = raw[3];
  float sum = v0 + v1 + v2 + v3;
  #pragma unroll
  for (int off = 32; off > 0; off >>= 1) sum += __shfl_down(sum, off, 64);
  __shared__ float sA[4], sB[4];
  int w = tid >> 6;
  if ((tid & 63) == 0) sA[w] = sum;
  __syncthreads();
  float mu = (sA[0] + sA[1] + sA[2] + sA[3]) * (1.f / 1024.f);
  float d0 = v0 - mu, d1 = v1 - mu, d2 = v2 - mu, d3 = v3 - mu;
  float s2 = d0 * d0 + d1 * d1 + d2 * d2 + d3 * d3;
  #pragma unroll
  for (int off = 32; off > 0; off >>= 1) s2 += __shfl_down(s2, off, 64);
  if ((tid & 63) == 0) sB[w] = s2;
  __syncthreads();
  float inv = rsqrtf((sB[0] + sB[1] + sB[2] + sB[3]) * (1.f / 1024.f) + 1e-6f);
  float4_t sv = *(const float4_t*)(sw + tid * 4);
  float4_t bv = *(const float4_t*)(bw + tid * 4);
  short4_t ov;
  ov[0] = (short)f2b(d0 * inv * sv[0] + bv[0]);
  ov[1] = (short)f2b(d1 * inv * sv[1] + bv[1]);
  ov[2] = (short)f2b(d2 * inv * sv[2] + bv[2]);
  ov[3] = (short)f2b(d3 * inv * sv[3] + bv[3]);
  *(short4_t*)(out + (size_t)row * 1024 + tid * 4) = ov;
}

// ---------------- MFMA GEMM: C[M,N] = A[M,K](bf16) * Bt[N,K](bf16)^T ----------------
// EPI: 0=none 1=+res 2=gelu(+bias) 3=+bias+res ; res/bias fp32 ; C dtype = TC
#define BM 128
#define BN 128
#define BKK 32
#define LDA 40

template<int EPI, typename TC>
__global__ __launch_bounds__(256)
void gemm_k(const u16* __restrict__ A, const u16* __restrict__ Bt,
            const float* __restrict__ bias, const float* __restrict__ res,
            TC* __restrict__ C, int M, int N, int K) {
  __shared__ __align__(16) short lA[BM * LDA];
  __shared__ __align__(16) short lB[BN * LDA];
  const int bn = blockIdx.x * BN;
  const int bm = blockIdx.y * BM;
  const int tid = threadIdx.x;
  const int lane = tid & 63;
  const int wave = tid >> 6;
  const int wy = wave >> 1, wx = wave & 1;
  const int quad = lane >> 4, l16 = lane & 15;

  float4_t acc[4][4];
  float4_t zz = {0.f, 0.f, 0.f, 0.f};
  #pragma unroll
  for (int i = 0; i < 4; ++i)
    #pragma unroll
    for (int j = 0; j < 4; ++j) acc[i][j] = zz;

  for (int k0 = 0; k0 < K; k0 += BKK) {
    __syncthreads();
    #pragma unroll
    for (int u = 0; u < 2; ++u) {
      int c = tid + u * 256;          // 0..511 chunks of 8 bf16
      int r = c >> 2, kc = c & 3;
      *(short8*)&lA[r * LDA + kc * 8] =
          *(const short8*)(A + (size_t)(bm + r) * K + k0 + kc * 8);
      *(short8*)&lB[r * LDA + kc * 8] =
          *(const short8*)(Bt + (size_t)(bn + r) * K + k0 + kc * 8);
    }
    __syncthreads();
    short8 af[4], bfr[4];
    #pragma unroll
    for (int i = 0; i < 4; ++i)
      af[i] = *(const short8*)&lA[(wy * 64 + i * 16 + l16) * LDA + quad * 8];
    #pragma unroll
    for (int j = 0; j < 4; ++j)
      bfr[j] = *(const short8*)&lB[(wx * 64 + j * 16 + l16) * LDA + quad * 8];
    #pragma unroll
    for (int i = 0; i < 4; ++i)
      #pragma unroll
      for (int j = 0; j < 4; ++j)
        acc[i][j] = __builtin_amdgcn_mfma_f32_16x16x32_bf16(af[i], bfr[j], acc[i][j], 0, 0, 0);
  }

  #pragma unroll
  for (int i = 0; i < 4; ++i) {
    int row = bm + wy * 64 + i * 16 + quad * 4;
    #pragma unroll
    for (int j = 0; j < 4; ++j) {
      int col = bn + wx * 64 + j * 16 + l16;
      #pragma unroll
      for (int v = 0; v < 4; ++v) {
        float x = acc[i][j][v];
        size_t idx = (size_t)(row + v) * N + col;
        if (EPI == 1) {
          x += res[idx];
        } else if (EPI == 2) {
          x = gelu_f(x + bias[col]);
        } else if (EPI == 3) {
          x += bias[col] + res[idx];
        }
        store_val(&C[idx], x);
      }
    }
  }
}

// ---------------- krep (per batch): sum k over block rows ----------------
__global__ __launch_bounds__(256)
void krep_k(const u16* __restrict__ K1, float* __restrict__ krep) {
  int idx = blockIdx.x * 256 + threadIdx.x;   // NB*1024 = 16384
  int col = idx & 1023;
  int n = idx >> 10;
  const u16* p = K1 + (size_t)n * 128 * 1024 + col;
  float s = 0.f;
  for (int i = 0; i < 128; ++i) s += b2f(p[(size_t)i * 1024]);
  krep[idx] = s;
}

// ---------------- sinkhorn (per batch): 16 blocks, one head each ----------------
__global__ __launch_bounds__(256)
void sinkhorn_k(const float* __restrict__ krep, const float* __restrict__ wsort,
                float* __restrict__ P) {
  int h = blockIdx.x;
  int t = threadIdx.x;
  int i = t >> 4, j = t & 15;
  __shared__ float la[16][17];
  __shared__ float red[16];
  float acc = 0.f;
  const float* kr = krep + (size_t)i * 1024 + h * 64;
  const float* ws = wsort + (size_t)h * 64 * 16 + j;
  for (int k = 0; k < 64; ++k) acc += kr[k] * ws[k * 16];
  acc = fminf(fmaxf(acc, -1e4f), 1e4f);   // inert for sane data
  la[i][j] = (j <= i) ? acc : -1e9f;
  __syncthreads();
  for (int it = 0; it < 5; ++it) {
    if (t < 16) {
      float m = -1e30f;
      for (int jj = 0; jj < 16; ++jj) m = fmaxf(m, la[t][jj]);
      float s = 0.f;
      for (int jj = 0; jj < 16; ++jj) s += __expf(la[t][jj] - m);
      red[t] = m + __logf(s);
    }
    __syncthreads();
    la[i][j] = (j <= i) ? la[i][j] - red[i] : -1e9f;
    __syncthreads();
    if (t < 16) {
      float m = -1e30f;
      for (int ii = 0; ii < 16; ++ii) m = fmaxf(m, la[ii][t]);
      float s = 0.f;
      for (int ii = 0; ii < 16; ++ii) s += __expf(la[ii][t] - m);
      red[t] = m + __logf(s);
    }
    __syncthreads();
    la[i][j] = (j <= i) ? la[i][j] - red[j] : -1e9f;
    __syncthreads();
  }
  P[((size_t)h * 16 + i) * 16 + j] = __expf(la[i][j]);
}

// ---------------- sorted block mix (per batch) ----------------
__global__ __launch_bounds__(256)
void sortmix_k(const float* __restrict__ P, const u16* __restrict__ K1,
               const u16* __restrict__ V1, u16* __restrict__ KS,
               u16* __restrict__ VS) {
  int t = blockIdx.x * 256 + threadIdx.x;     // 2048*256 threads (4 cols each)
  int col = (t & 255) * 4;
  int rest = t >> 8;                          // i*128 + s
  int i = rest >> 7, s = rest & 127;
  int h = col >> 6;
  const float* Pr = P + ((size_t)h * 16 + i) * 16;
  size_t base = (size_t)s * 1024 + col;
  float ka[4] = {0, 0, 0, 0}, va[4] = {0, 0, 0, 0};
  for (int j = 0; j <= i; ++j) {   // P[i][j]==0 for j>i (causal mask)
    float p = Pr[j];
    short4_t kk = *(const short4_t*)&K1[base + (size_t)j * 131072];
    short4_t vv = *(const short4_t*)&V1[base + (size_t)j * 131072];
    #pragma unroll
    for (int e = 0; e < 4; ++e) {
      ka[e] += p * b2f((u16)kk[e]);
      va[e] += p * b2f((u16)vv[e]);
    }
  }
  size_t ob = ((size_t)(i * 128 + s)) * 1024 + col;
  short4_t ok, ov;
  #pragma unroll
  for (int e = 0; e < 4; ++e) { ok[e] = (short)f2b(ka[e]); ov[e] = (short)f2b(va[e]); }
  *(short4_t*)&KS[ob] = ok;
  *(short4_t*)&VS[ob] = ov;
}

// ---------------- flash inner loop (64-dim head, keys from LDS) ----------------
__device__ __forceinline__ void flash_tile(const u16* Kt, const u16* Vt,
                                           const float* q, int sEnd,
                                           float& m, float& l, float* o) {
  for (int s = 0; s < sEnd; ++s) {
    float sc = 0.f;
    #pragma unroll
    for (int c = 0; c < 8; ++c) {
      short8 kv = *(const short8*)&Kt[s * 64 + c * 8];
      #pragma unroll
      for (int e = 0; e < 8; ++e) sc += q[c * 8 + e] * b2f((u16)kv[e]);
    }
    sc = fminf(sc * SCALE_, 80.f);   // clamp: inert for sane data
    if (sc <= m) {
      float w = __expf(sc - m);
      l += w;
      #pragma unroll
      for (int c = 0; c < 8; ++c) {
        short8 vv = *(const short8*)&Vt[s * 64 + c * 8];
        #pragma unroll
        for (int e = 0; e < 8; ++e) o[c * 8 + e] += w * b2f((u16)vv[e]);
      }
    } else {
      float cr = __expf(m - sc);
      m = sc;
      l = l * cr + 1.f;
      #pragma unroll
      for (int c = 0; c < 8; ++c) {
        short8 vv = *(const short8*)&Vt[s * 64 + c * 8];
        #pragma unroll
        for (int e = 0; e < 8; ++e) o[c * 8 + e] = o[c * 8 + e] * cr + b2f((u16)vv[e]);
      }
    }
  }
}

// ---------------- sinkhorn self-attention (per batch) ----------------
__global__ __launch_bounds__(256)
void attn1_k(const u16* __restrict__ Q, const u16* __restrict__ K1,
             const u16* __restrict__ V1, const u16* __restrict__ KS,
             const u16* __restrict__ VS, u16* __restrict__ O) {
  __shared__ __align__(16) u16 kt[2][128 * 64];
  __shared__ __align__(16) u16 vt[2][128 * 64];
  const int blk = blockIdx.x;                 // 256 = n + 16*h
  const int n = blk & 15, h = blk >> 4;
  const int tid = threadIdx.x;
  const int r = tid & 127, half = tid >> 7;
  const size_t tileBase = ((size_t)(n * 128)) * 1024 + h * 64;

  #pragma unroll
  for (int c = 0; c < 4; ++c) {
    int cc = tid + c * 256;
    int s = cc >> 3, dd = (cc & 7) * 8;
    size_t g = tileBase + (size_t)s * 1024 + dd;
    int lo = s * 64 + dd;
    *(short8*)&kt[0][lo] = *(const short8*)&K1[g];
    *(short8*)&vt[0][lo] = *(const short8*)&V1[g];
    *(short8*)&kt[1][lo] = *(const short8*)&KS[g];
    *(short8*)&vt[1][lo] = *(const short8*)&VS[g];
  }

  float q[64], o[64];
  const u16* qp = Q + tileBase + (size_t)r * 1024;
  #pragma unroll
  for (int c = 0; c < 8; ++c) {
    short8 u = *(const short8*)&qp[c * 8];
    #pragma unroll
    for (int e = 0; e < 8; ++e) { q[c * 8 + e] = b2f((u16)u[e]); o[c * 8 + e] = 0.f; }
  }
  float m = -1e30f, l = 0.f;
  __syncthreads();
  flash_tile(&kt[half][0], &vt[half][0], q, half ? 128 : (r + 1), m, l, o);
  __syncthreads();
  float* o2 = (float*)&kt[0][0];     // 32KB reuse (spans kt[0..1])
  float* ml2 = (float*)&vt[0][0];
  if (half) {
    #pragma unroll
    for (int d = 0; d < 64; ++d) o2[r * 64 + d] = o[d];
    ml2[r] = m;
    ml2[128 + r] = l;
  }
  __syncthreads();
  if (!half) {
    float m2 = ml2[r], l2 = ml2[128 + r];
    float mn = fmaxf(m, m2);
    float c1 = __expf(m - mn), c2 = __expf(m2 - mn);
    float inv = 1.f / fmaxf(l * c1 + l2 * c2, 1e-30f);
    u16* op = O + tileBase + (size_t)r * 1024;
    #pragma unroll
    for (int c = 0; c < 16; ++c) {
      short4_t ov;
      #pragma unroll
      for (int e = 0; e < 4; ++e)
        ov[e] = (short)f2b((o[c * 4 + e] * c1 + o2[r * 64 + c * 4 + e] * c2) * inv);
      *(short4_t*)&op[c * 4] = ov;
    }
  }
}

// ---------------- cross attention (per batch, 1024 encoded keys) ----------------
__global__ __launch_bounds__(256)
void xattn_k(const u16* __restrict__ Q, const u16* __restrict__ K2,
             const u16* __restrict__ V2, u16* __restrict__ O) {
  __shared__ __align__(16) u16 kt[2][128 * 64];
  __shared__ __align__(16) u16 vt[2][128 * 64];
  const int blk = blockIdx.x;                 // 256 = qt + 16*h
  const int qt = blk & 15, h = blk >> 4;
  const int tid = threadIdx.x;
  const int r = tid & 127, half = tid >> 7;

  float q[64], o[64];
  const u16* qp = Q + ((size_t)(qt * 128 + r)) * 1024 + h * 64;
  #pragma unroll
  for (int c = 0; c < 8; ++c) {
    short8 u = *(const short8*)&qp[c * 8];
    #pragma unroll
    for (int e = 0; e < 8; ++e) { q[c * 8 + e] = b2f((u16)u[e]); o[c * 8 + e] = 0.f; }
  }
  float m = -1e30f, l = 0.f;

  for (int stage = 0; stage < 4; ++stage) {
    __syncthreads();
    size_t kb0 = ((size_t)(stage * 128)) * 1024 + h * 64;
    size_t kb1 = ((size_t)((4 + stage) * 128)) * 1024 + h * 64;
    #pragma unroll
    for (int c = 0; c < 4; ++c) {
      int cc = tid + c * 256;
      int s = cc >> 3, dd = (cc & 7) * 8;
      int lo = s * 64 + dd;
      size_t g0 = kb0 + (size_t)s * 1024 + dd;
      size_t g1 = kb1 + (size_t)s * 1024 + dd;
      *(short8*)&kt[0][lo] = *(const short8*)&K2[g0];
      *(short8*)&vt[0][lo] = *(const short8*)&V2[g0];
      *(short8*)&kt[1][lo] = *(const short8*)&K2[g1];
      *(short8*)&vt[1][lo] = *(const short8*)&V2[g1];
    }
    __syncthreads();
    flash_tile(&kt[half][0], &vt[half][0], q, 128, m, l, o);
  }
  __syncthreads();
  float* o2 = (float*)&kt[0][0];
  float* ml2 = (float*)&vt[0][0];
  if (half) {
    #pragma unroll
    for (int d = 0; d < 64; ++d) o2[r * 64 + d] = o[d];
    ml2[r] = m;
    ml2[128 + r] = l;
  }
  __syncthreads();
  if (!half) {
    float m2 = ml2[r], l2 = ml2[128 + r];
    float mn = fmaxf(m, m2);
    float c1 = __expf(m - mn), c2 = __expf(m2 - mn);
    float inv = 1.f / fmaxf(l * c1 + l2 * c2, 1e-30f);
    u16* op = O + ((size_t)(qt * 128 + r)) * 1024 + h * 64;
    #pragma unroll
    for (int c = 0; c < 16; ++c) {
      short4_t ov;
      #pragma unroll
      for (int e = 0; e < 4; ++e)
        ov[e] = (short)f2b((o[c * 4 + e] * c1 + o2[r * 64 + c * 4 + e] * c2) * inv);
      *(short4_t*)&op[c * 4] = ov;
    }
  }
}

// ---------------- host ----------------
// ALL d_in / d_out are FP32 (reference dtype). Internals bf16 (threshold is
// bf16-scale). Per-batch loop keeps ws usage at ~36 MB.
extern "C" void kernel_launch(void* const* d_in, const int* in_sizes, int n_in,
                              void* d_out, int out_size, void* d_ws, size_t ws_size,
                              hipStream_t stream) {
  const float* targets = (const float*)d_in[0];
  const float* encoded = (const float*)d_in[1];
  const float* ln1s = (const float*)d_in[2];
  const float* ln1b = (const float*)d_in[3];
  const float* ln2s = (const float*)d_in[4];
  const float* ln2b = (const float*)d_in[5];
  const float* ln3s = (const float*)d_in[6];
  const float* ln3b = (const float*)d_in[7];
  const float* wq1 = (const float*)d_in[8];
  const float* wk1 = (const float*)d_in[9];
  const float* wv1 = (const float*)d_in[10];
  const float* wo1 = (const float*)d_in[11];
  const float* wsort = (const float*)d_in[12];
  const float* wq2 = (const float*)d_in[13];
  const float* wk2 = (const float*)d_in[14];
  const float* wv2 = (const float*)d_in[15];
  const float* wo2 = (const float*)d_in[16];
  const float* w1 = (const float*)d_in[17];
  const float* b1 = (const float*)d_in[18];
  const float* w2 = (const float*)d_in[19];
  const float* b2 = (const float*)d_in[20];
  float* out = (float*)d_out;
  (void)in_sizes; (void)n_in; (void)out_size; (void)ws_size;

  char* ws = (char*)d_ws;
  size_t off = 0;
  auto alloc = [&](size_t n) -> char* {
    char* p = ws + off;
    off += (n + 255) & ~(size_t)255;
    return p;
  };
  const size_t SLC = (size_t)LT_ * D_;              // 2M elems per batch

  u16* wT  = (u16*)alloc((size_t)1024 * 1024 * 2);  // 2MB transposed weight chunk
  u16* XLN = (u16*)alloc(SLC * 2);
  u16* Qb  = (u16*)alloc(SLC * 2);
  u16* Kb  = (u16*)alloc(SLC * 2);
  u16* Vb  = (u16*)alloc(SLC * 2);
  u16* KSb = (u16*)alloc(SLC * 2);
  u16* VSb = (u16*)alloc(SLC * 2);
  u16* Ob  = (u16*)alloc(SLC * 2);
  u16* Hc  = (u16*)alloc(SLC * 2);                  // MLP hidden chunk [2048,1024]
  u16* Eb  = (u16*)alloc((size_t)LE_ * D_ * 2);     // encoded -> bf16
  float* KREP = (float*)alloc((size_t)NB_ * 1024 * 4);
  float* Pm = (float*)alloc((size_t)H_ * NB_ * NB_ * 4);

  // transpose a [1024 x 1024] fp32 view (row stride rs) into bf16 wT
  auto T = [&](const float* src, int rs) {
    transpose_k<<<dim3(32, 32), 256, 0, stream>>>(src, wT, 1024, rs);
  };

  for (int b = 0; b < B_; ++b) {
    const float* tgt_b = targets + (size_t)b * SLC;
    const float* enc_b = encoded + (size_t)b * LE_ * D_;
    float* out_b = out + (size_t)b * SLC;

    // x = LN(targets)
    ln_k<<<2048, 256, 0, stream>>>(tgt_b, ln1s, ln1b, XLN);
    // q/k/v projections
    T(wq1, 1024);
    gemm_k<0, u16><<<dim3(8, 16), 256, 0, stream>>>(XLN, wT, nullptr, nullptr, Qb, 2048, 1024, 1024);
    T(wk1, 1024);
    gemm_k<0, u16><<<dim3(8, 16), 256, 0, stream>>>(XLN, wT, nullptr, nullptr, Kb, 2048, 1024, 1024);
    T(wv1, 1024);
    gemm_k<0, u16><<<dim3(8, 16), 256, 0, stream>>>(XLN, wT, nullptr, nullptr, Vb, 2048, 1024, 1024);
    // sortnet
    krep_k<<<64, 256, 0, stream>>>(Kb, KREP);
    sinkhorn_k<<<16, 256, 0, stream>>>(KREP, wsort, Pm);
    sortmix_k<<<2048, 256, 0, stream>>>(Pm, Kb, Vb, KSb, VSb);
    // self attention
    attn1_k<<<256, 256, 0, stream>>>(Qb, Kb, Vb, KSb, VSb, Ob);
    // x2 = o @ wo1 + targets  (-> out_b fp32)
    T(wo1, 1024);
    gemm_k<1, float><<<dim3(8, 16), 256, 0, stream>>>(Ob, wT, nullptr, tgt_b, out_b, 2048, 1024, 1024);
    // cross attention
    ln_k<<<2048, 256, 0, stream>>>(out_b, ln2s, ln2b, XLN);
    conv_k<<<1024, 256, 0, stream>>>(enc_b, Eb);
    T(wq2, 1024);
    gemm_k<0, u16><<<dim3(8, 16), 256, 0, stream>>>(XLN, wT, nullptr, nullptr, Qb, 2048, 1024, 1024);
    T(wk2, 1024);
    gemm_k<0, u16><<<dim3(8, 8), 256, 0, stream>>>(Eb, wT, nullptr, nullptr, Kb, 1024, 1024, 1024);
    T(wv2, 1024);
    gemm_k<0, u16><<<dim3(8, 8), 256, 0, stream>>>(Eb, wT, nullptr, nullptr, Vb, 1024, 1024, 1024);
    xattn_k<<<256, 256, 0, stream>>>(Qb, Kb, Vb, Ob);
    // y = o2 @ wo2 + x2  (res==C==out_b fp32: same-thread same-index)
    T(wo2, 1024);
    gemm_k<1, float><<<dim3(8, 16), 256, 0, stream>>>(Ob, wT, nullptr, out_b, out_b, 2048, 1024, 1024);
    // MLP in 4 column chunks of 1024, accumulated into out_b (fp32)
    ln_k<<<2048, 256, 0, stream>>>(out_b, ln3s, ln3b, XLN);
    for (int c = 0; c < 4; ++c) {
      T(w1 + (size_t)c * 1024, 4096);                       // w1[:, c*1024:+1024]^T
      gemm_k<2, u16><<<dim3(8, 16), 256, 0, stream>>>(XLN, wT, b1 + c * 1024, nullptr, Hc,
                                                      2048, 1024, 1024);
      T(w2 + (size_t)c * 1024 * 1024, 1024);                // w2[c*1024:+1024, :]^T
      if (c < 3)
        gemm_k<1, float><<<dim3(8, 16), 256, 0, stream>>>(Hc, wT, nullptr, out_b, out_b,
                                                          2048, 1024, 1024);
      else
        gemm_k<3, float><<<dim3(8, 16), 256, 0, stream>>>(Hc, wT, b2, out_b, out_b,
                                                          2048, 1024, 1024);
    }
  }
}

// Round 5
// 979.041 us; speedup vs baseline: 4.2716x; 4.2716x over previous
//
#include <hip/hip_runtime.h>

typedef unsigned short u16;
typedef __attribute__((ext_vector_type(8))) short short8;
typedef __attribute__((ext_vector_type(4))) short short4_t;
typedef __attribute__((ext_vector_type(4))) float float4_t;

#define B_ 4
#define LT_ 2048
#define LE_ 1024
#define D_ 1024
#define H_ 16
#define HD_ 64
#define NB_ 16
#define BS_ 128
#define M_ 4096
#define SCALE_ 0.125f

__device__ __forceinline__ float b2f(u16 u) {
  union { unsigned int i; float f; } v; v.i = ((unsigned int)u) << 16; return v.f;
}
__device__ __forceinline__ u16 f2b(float f) {
  union { float f; unsigned int i; } v; v.f = f;
  unsigned int x = v.i;
  return (u16)((x + 0x7fffu + ((x >> 16) & 1u)) >> 16);
}
__device__ __forceinline__ float gelu_f(float u) {
  float t = 0.7978845608028654f * (u + 0.044715f * u * u * u);
  return 0.5f * u * (1.f + tanhf(t));
}
__device__ __forceinline__ void store_val(u16* p, float x) { *p = f2b(x); }
__device__ __forceinline__ void store_val(float* p, float x) { *p = x; }

// ---------------- fp32 -> bf16 convert ----------------
__global__ __launch_bounds__(256)
void conv_k(const float* __restrict__ in, u16* __restrict__ out) {
  int i = (blockIdx.x * 256 + threadIdx.x) * 4;
  float4_t v = *(const float4_t*)(in + i);
  short4_t o;
  o[0] = (short)f2b(v[0]); o[1] = (short)f2b(v[1]);
  o[2] = (short)f2b(v[2]); o[3] = (short)f2b(v[3]);
  *(short4_t*)(out + i) = o;
}

// ---------------- transpose fp32 [R,Csub] (row stride) -> bf16 [Csub,R] ----------------
__global__ __launch_bounds__(256)
void transpose_k(const float* __restrict__ in, u16* __restrict__ out, int R, int rstride) {
  __shared__ u16 tile[32][33];
  int bx = blockIdx.x * 32, by = blockIdx.y * 32;
  int tx = threadIdx.x & 31, ty = threadIdx.x >> 5;
  #pragma unroll
  for (int y = ty; y < 32; y += 8)
    tile[y][tx] = f2b(in[(size_t)(by + y) * rstride + bx + tx]);
  __syncthreads();
  #pragma unroll
  for (int y = ty; y < 32; y += 8)
    out[(size_t)(bx + y) * R + by + tx] = tile[tx][y];
}

// ---------------- layernorm (rows of 1024): fp32 in -> bf16 out ----------------
__global__ __launch_bounds__(256)
void ln_k(const float* __restrict__ x, const float* __restrict__ sw,
          const float* __restrict__ bw, u16* __restrict__ out) {
  int row = blockIdx.x, tid = threadIdx.x;
  const float* xr = x + (size_t)row * 1024 + tid * 4;
  float4_t raw = *(const float4_t*)xr;
  float v0 = raw[0], v1 = raw[1], v2 = raw[2], v3 = raw[3];
  float sum = v0 + v1 + v2 + v3;
  #pragma unroll
  for (int off = 32; off > 0; off >>= 1) sum += __shfl_down(sum, off, 64);
  __shared__ float sA[4], sB[4];
  int w = tid >> 6;
  if ((tid & 63) == 0) sA[w] = sum;
  __syncthreads();
  float mu = (sA[0] + sA[1] + sA[2] + sA[3]) * (1.f / 1024.f);
  float d0 = v0 - mu, d1 = v1 - mu, d2 = v2 - mu, d3 = v3 - mu;
  float s2 = d0 * d0 + d1 * d1 + d2 * d2 + d3 * d3;
  #pragma unroll
  for (int off = 32; off > 0; off >>= 1) s2 += __shfl_down(s2, off, 64);
  if ((tid & 63) == 0) sB[w] = s2;
  __syncthreads();
  float inv = rsqrtf((sB[0] + sB[1] + sB[2] + sB[3]) * (1.f / 1024.f) + 1e-6f);
  float4_t sv = *(const float4_t*)(sw + tid * 4);
  float4_t bv = *(const float4_t*)(bw + tid * 4);
  short4_t ov;
  ov[0] = (short)f2b(d0 * inv * sv[0] + bv[0]);
  ov[1] = (short)f2b(d1 * inv * sv[1] + bv[1]);
  ov[2] = (short)f2b(d2 * inv * sv[2] + bv[2]);
  ov[3] = (short)f2b(d3 * inv * sv[3] + bv[3]);
  *(short4_t*)(out + (size_t)row * 1024 + tid * 4) = ov;
}

// ---------------- MFMA GEMM: C[M,N] = A[M,K](bf16) * Bt[N,K](bf16)^T ----------------
// EPI: 0=none 1=+res 2=gelu(+bias) 3=+bias+res ; res/bias fp32 ; C dtype = TC
#define BM 128
#define BN 128
#define BKK 32
#define LDA 40

template<int EPI, typename TC>
__global__ __launch_bounds__(256)
void gemm_k(const u16* __restrict__ A, const u16* __restrict__ Bt,
            const float* __restrict__ bias, const float* __restrict__ res,
            TC* __restrict__ C, int M, int N, int K) {
  __shared__ __align__(16) short lA[BM * LDA];
  __shared__ __align__(16) short lB[BN * LDA];
  const int bn = blockIdx.x * BN;
  const int bm = blockIdx.y * BM;
  const int tid = threadIdx.x;
  const int lane = tid & 63;
  const int wave = tid >> 6;
  const int wy = wave >> 1, wx = wave & 1;
  const int quad = lane >> 4, l16 = lane & 15;

  float4_t acc[4][4];
  float4_t zz = {0.f, 0.f, 0.f, 0.f};
  #pragma unroll
  for (int i = 0; i < 4; ++i)
    #pragma unroll
    for (int j = 0; j < 4; ++j) acc[i][j] = zz;

  for (int k0 = 0; k0 < K; k0 += BKK) {
    __syncthreads();
    #pragma unroll
    for (int u = 0; u < 2; ++u) {
      int c = tid + u * 256;          // 0..511 chunks of 8 bf16
      int r = c >> 2, kc = c & 3;
      *(short8*)&lA[r * LDA + kc * 8] =
          *(const short8*)(A + (size_t)(bm + r) * K + k0 + kc * 8);
      *(short8*)&lB[r * LDA + kc * 8] =
          *(const short8*)(Bt + (size_t)(bn + r) * K + k0 + kc * 8);
    }
    __syncthreads();
    short8 af[4], bfr[4];
    #pragma unroll
    for (int i = 0; i < 4; ++i)
      af[i] = *(const short8*)&lA[(wy * 64 + i * 16 + l16) * LDA + quad * 8];
    #pragma unroll
    for (int j = 0; j < 4; ++j)
      bfr[j] = *(const short8*)&lB[(wx * 64 + j * 16 + l16) * LDA + quad * 8];
    #pragma unroll
    for (int i = 0; i < 4; ++i)
      #pragma unroll
      for (int j = 0; j < 4; ++j)
        acc[i][j] = __builtin_amdgcn_mfma_f32_16x16x32_bf16(af[i], bfr[j], acc[i][j], 0, 0, 0);
  }

  #pragma unroll
  for (int i = 0; i < 4; ++i) {
    int row = bm + wy * 64 + i * 16 + quad * 4;
    #pragma unroll
    for (int j = 0; j < 4; ++j) {
      int col = bn + wx * 64 + j * 16 + l16;
      #pragma unroll
      for (int v = 0; v < 4; ++v) {
        float x = acc[i][j][v];
        size_t idx = (size_t)(row + v) * N + col;
        if (EPI == 1) {
          x += res[idx];
        } else if (EPI == 2) {
          x = gelu_f(x + bias[col]);
        } else if (EPI == 3) {
          x += bias[col] + res[idx];
        }
        store_val(&C[idx], x);
      }
    }
  }
}

// ---------------- krep: sum k over block rows (b decoded from idx) ----------------
__global__ __launch_bounds__(256)
void krep_k(const u16* __restrict__ K1, float* __restrict__ krep) {
  int idx = blockIdx.x * 256 + threadIdx.x;   // (#batches)*NB*1024
  int col = idx & 1023;
  int bn = idx >> 10;
  const u16* p = K1 + (size_t)bn * 128 * 1024 + col;
  float s = 0.f;
  for (int i = 0; i < 128; ++i) s += b2f(p[(size_t)i * 1024]);
  krep[idx] = s;
}

// ---------------- sinkhorn: grid = (#batches)*H, one (b,h) each ----------------
__global__ __launch_bounds__(256)
void sinkhorn_k(const float* __restrict__ krep, const float* __restrict__ wsort,
                float* __restrict__ P) {
  int bh = blockIdx.x;
  int b = bh >> 4, h = bh & 15;
  int t = threadIdx.x;
  int i = t >> 4, j = t & 15;
  __shared__ float la[16][17];
  __shared__ float red[16];
  float acc = 0.f;
  const float* kr = krep + ((size_t)b * 16 + i) * 1024 + h * 64;
  const float* ws = wsort + (size_t)h * 64 * 16 + j;
  for (int k = 0; k < 64; ++k) acc += kr[k] * ws[k * 16];
  la[i][j] = (j <= i) ? acc : -1e9f;
  __syncthreads();
  for (int it = 0; it < 5; ++it) {
    if (t < 16) {
      float m = -1e30f;
      for (int jj = 0; jj < 16; ++jj) m = fmaxf(m, la[t][jj]);
      float s = 0.f;
      for (int jj = 0; jj < 16; ++jj) s += __expf(la[t][jj] - m);
      red[t] = m + __logf(s);
    }
    __syncthreads();
    la[i][j] = (j <= i) ? la[i][j] - red[i] : -1e9f;
    __syncthreads();
    if (t < 16) {
      float m = -1e30f;
      for (int ii = 0; ii < 16; ++ii) m = fmaxf(m, la[ii][t]);
      float s = 0.f;
      for (int ii = 0; ii < 16; ++ii) s += __expf(la[ii][t] - m);
      red[t] = m + __logf(s);
    }
    __syncthreads();
    la[i][j] = (j <= i) ? la[i][j] - red[j] : -1e9f;
    __syncthreads();
  }
  P[((size_t)bh * 16 + i) * 16 + j] = __expf(la[i][j]);
}

// ---------------- sorted block mix (b decoded from idx) ----------------
__global__ __launch_bounds__(256)
void sortmix_k(const float* __restrict__ P, const u16* __restrict__ K1,
               const u16* __restrict__ V1, u16* __restrict__ KS,
               u16* __restrict__ VS) {
  int t = blockIdx.x * 256 + threadIdx.x;     // (#batches)*2048*256 (4 cols each)
  int col = (t & 255) * 4;
  int rest = t >> 8;                          // b*2048 + i*128 + s
  int b = rest >> 11, is = rest & 2047, i = is >> 7, s = is & 127;
  int h = col >> 6;
  const float* Pr = P + (((size_t)(b * 16 + h)) * 16 + i) * 16;
  size_t base = ((size_t)(b * 2048 + s)) * 1024 + col;
  float ka[4] = {0, 0, 0, 0}, va[4] = {0, 0, 0, 0};
  for (int j = 0; j <= i; ++j) {   // P[i][j]==0 for j>i (causal mask)
    float p = Pr[j];
    short4_t kk = *(const short4_t*)&K1[base + (size_t)j * 131072];
    short4_t vv = *(const short4_t*)&V1[base + (size_t)j * 131072];
    #pragma unroll
    for (int e = 0; e < 4; ++e) {
      ka[e] += p * b2f((u16)kk[e]);
      va[e] += p * b2f((u16)vv[e]);
    }
  }
  size_t ob = ((size_t)(b * 2048 + i * 128 + s)) * 1024 + col;
  short4_t ok, ov;
  #pragma unroll
  for (int e = 0; e < 4; ++e) { ok[e] = (short)f2b(ka[e]); ov[e] = (short)f2b(va[e]); }
  *(short4_t*)&KS[ob] = ok;
  *(short4_t*)&VS[ob] = ov;
}

// ---------------- MFMA flash attention ----------------
// Block = 256 thr = 4 waves; one (b, h, 128-row q-tile). Wave wv owns q rows
// [wv*32, wv*32+32). Q A-frags in registers (constant across k-tiles); K in
// LDS row-major (stride 72: 2-way bank alias = free); V staged TRANSPOSED
// (VT[64][136]) so PV B-frags are contiguous ds_read_b128; P written in
// C-layout / read in A-layout via per-wave LDS rows (no barrier needed:
// same-wave dependency, lgkmcnt ordering).
// CROSS=0: 2 tiles (local causal + sorted). CROSS=1: 8 tiles over LE keys.
#define KLS 72
#define VTS 136
#define PLS 136

template<int CROSS>
__global__ __launch_bounds__(256)
void attn_mfma_k(const u16* __restrict__ Q, const u16* __restrict__ Ka,
                 const u16* __restrict__ Va, const u16* __restrict__ Kb2,
                 const u16* __restrict__ Vb2, u16* __restrict__ O) {
  __shared__ __align__(16) u16 kls[128 * KLS];
  __shared__ __align__(16) u16 vtls[64 * VTS];
  __shared__ __align__(16) u16 pls[128 * PLS];
  const int blk = blockIdx.x;
  const int n = blk & 15, h = (blk >> 4) & 15, b = blk >> 8;
  const int tid = threadIdx.x, lane = tid & 63, wv = tid >> 6;
  const int quad = lane >> 4, l16 = lane & 15;
  const int m0 = wv * 32;
  const size_t qrowbase = (size_t)b * 2048 + n * 128;

  short8 qa[2][2];
  #pragma unroll
  for (int mi = 0; mi < 2; ++mi)
    #pragma unroll
    for (int ks = 0; ks < 2; ++ks)
      qa[mi][ks] = *(const short8*)&Q[(qrowbase + m0 + mi * 16 + l16) * 1024 +
                                      h * 64 + ks * 32 + quad * 8];

  float4_t acc_o[2][4];
  float mrow[2][4], lrow[2][4];
  #pragma unroll
  for (int mi = 0; mi < 2; ++mi)
    #pragma unroll
    for (int dn = 0; dn < 4; ++dn) acc_o[mi][dn] = {0.f, 0.f, 0.f, 0.f};
  #pragma unroll
  for (int mi = 0; mi < 2; ++mi)
    #pragma unroll
    for (int v = 0; v < 4; ++v) { mrow[mi][v] = -1e30f; lrow[mi][v] = 0.f; }

  const int NT = CROSS ? 8 : 2;
  for (int t = 0; t < NT; ++t) {
    const u16 *Kg, *Vg;
    bool causal = false;
    if (CROSS) {
      size_t kb = ((size_t)b * 1024 + t * 128) * 1024 + h * 64;
      Kg = Ka + kb; Vg = Va + kb;
    } else if (t == 0) {
      size_t kb = qrowbase * 1024 + h * 64;
      Kg = Ka + kb; Vg = Va + kb; causal = true;
    } else {
      size_t kb = qrowbase * 1024 + h * 64;
      Kg = Kb2 + kb; Vg = Vb2 + kb;
    }
    __syncthreads();                   // prior tile's LDS readers done
    #pragma unroll
    for (int i = 0; i < 4; ++i) {
      int c = tid + i * 256;
      int row = c >> 3, dd = (c & 7) * 8;
      short8 kv = *(const short8*)&Kg[(size_t)row * 1024 + dd];
      *(short8*)&kls[row * KLS + dd] = kv;
      short8 vv = *(const short8*)&Vg[(size_t)row * 1024 + dd];
      #pragma unroll
      for (int e = 0; e < 8; ++e) vtls[(dd + e) * VTS + row] = (u16)vv[e];
    }
    __syncthreads();

    // S = Q K^T (scaled later); acc_s[mi][nj]: rows m0+mi*16+quad*4+v, col nj*16+l16
    float4_t s[2][8];
    #pragma unroll
    for (int mi = 0; mi < 2; ++mi)
      #pragma unroll
      for (int nj = 0; nj < 8; ++nj) s[mi][nj] = {0.f, 0.f, 0.f, 0.f};
    #pragma unroll
    for (int nj = 0; nj < 8; ++nj) {
      short8 b0 = *(const short8*)&kls[(nj * 16 + l16) * KLS + quad * 8];
      short8 b1 = *(const short8*)&kls[(nj * 16 + l16) * KLS + 32 + quad * 8];
      #pragma unroll
      for (int mi = 0; mi < 2; ++mi) {
        s[mi][nj] = __builtin_amdgcn_mfma_f32_16x16x32_bf16(qa[mi][0], b0, s[mi][nj], 0, 0, 0);
        s[mi][nj] = __builtin_amdgcn_mfma_f32_16x16x32_bf16(qa[mi][1], b1, s[mi][nj], 0, 0, 0);
      }
    }
    // scale + causal mask + online softmax
    #pragma unroll
    for (int mi = 0; mi < 2; ++mi) {
      #pragma unroll
      for (int v = 0; v < 4; ++v) {
        int rowl = m0 + mi * 16 + quad * 4 + v;
        float mx = -1e30f;
        #pragma unroll
        for (int nj = 0; nj < 8; ++nj) {
          float x = s[mi][nj][v] * SCALE_;
          if (causal && (nj * 16 + l16 > rowl)) x = -1e30f;
          s[mi][nj][v] = x;
          mx = fmaxf(mx, x);
        }
        #pragma unroll
        for (int off = 1; off < 16; off <<= 1) mx = fmaxf(mx, __shfl_xor(mx, off, 64));
        float mn = fmaxf(mrow[mi][v], mx);
        float cr = __expf(mrow[mi][v] - mn);
        mrow[mi][v] = mn;
        float rs = 0.f;
        #pragma unroll
        for (int nj = 0; nj < 8; ++nj) {
          float p = __expf(s[mi][nj][v] - mn);
          s[mi][nj][v] = p;
          rs += p;
        }
        #pragma unroll
        for (int off = 1; off < 16; off <<= 1) rs += __shfl_xor(rs, off, 64);
        lrow[mi][v] = lrow[mi][v] * cr + rs;
        #pragma unroll
        for (int dn = 0; dn < 4; ++dn) acc_o[mi][dn][v] *= cr;
        #pragma unroll
        for (int nj = 0; nj < 8; ++nj)
          pls[rowl * PLS + nj * 16 + l16] = f2b(s[mi][nj][v]);
      }
    }
    // O += P V  (P read same-wave; VT b-frags contiguous)
    #pragma unroll
    for (int ks = 0; ks < 4; ++ks) {
      short8 a0 = *(const short8*)&pls[(m0 + l16) * PLS + ks * 32 + quad * 8];
      short8 a1 = *(const short8*)&pls[(m0 + 16 + l16) * PLS + ks * 32 + quad * 8];
      #pragma unroll
      for (int dn = 0; dn < 4; ++dn) {
        short8 bv = *(const short8*)&vtls[(dn * 16 + l16) * VTS + ks * 32 + quad * 8];
        acc_o[0][dn] = __builtin_amdgcn_mfma_f32_16x16x32_bf16(a0, bv, acc_o[0][dn], 0, 0, 0);
        acc_o[1][dn] = __builtin_amdgcn_mfma_f32_16x16x32_bf16(a1, bv, acc_o[1][dn], 0, 0, 0);
      }
    }
  }
  // epilogue: O / l -> bf16
  #pragma unroll
  for (int mi = 0; mi < 2; ++mi)
    #pragma unroll
    for (int v = 0; v < 4; ++v) {
      int rowl = m0 + mi * 16 + quad * 4 + v;
      float inv = 1.f / lrow[mi][v];
      #pragma unroll
      for (int dn = 0; dn < 4; ++dn)
        O[(qrowbase + rowl) * 1024 + h * 64 + dn * 16 + l16] =
            f2b(acc_o[mi][dn][v] * inv);
    }
}

// ---------------- host ----------------
extern "C" void kernel_launch(void* const* d_in, const int* in_sizes, int n_in,
                              void* d_out, int out_size, void* d_ws, size_t ws_size,
                              hipStream_t stream) {
  const float* targets = (const float*)d_in[0];
  const float* encoded = (const float*)d_in[1];
  const float* ln1s = (const float*)d_in[2];
  const float* ln1b = (const float*)d_in[3];
  const float* ln2s = (const float*)d_in[4];
  const float* ln2b = (const float*)d_in[5];
  const float* ln3s = (const float*)d_in[6];
  const float* ln3b = (const float*)d_in[7];
  const float* wq1 = (const float*)d_in[8];
  const float* wk1 = (const float*)d_in[9];
  const float* wv1 = (const float*)d_in[10];
  const float* wo1 = (const float*)d_in[11];
  const float* wsort = (const float*)d_in[12];
  const float* wq2 = (const float*)d_in[13];
  const float* wk2 = (const float*)d_in[14];
  const float* wv2 = (const float*)d_in[15];
  const float* wo2 = (const float*)d_in[16];
  const float* w1 = (const float*)d_in[17];
  const float* b1 = (const float*)d_in[18];
  const float* w2 = (const float*)d_in[19];
  const float* b2 = (const float*)d_in[20];
  float* out = (float*)d_out;
  (void)in_sizes; (void)n_in; (void)out_size;

  char* ws = (char*)d_ws;
  size_t off = 0;
  auto alloc = [&](size_t n) -> char* {
    char* p = ws + off;
    off += (n + 255) & ~(size_t)255;
    return p;
  };

  const size_t NTD = (size_t)B_ * LT_ * D_;         // 8.4M elems
  const size_t NEED_BIG = (size_t)(8 * 2 + 8 + 8) * 1024 * 1024   // weights bf16
                        + (size_t)LE_ * B_ * D_ * 2                // Eb
                        + NTD * 2 * 7                              // XLN + 6 act
                        + (1u << 20);                              // small + slack

  if (ws_size >= NEED_BIG) {
    // ---------- whole-batch path ----------
    u16* wq1t = (u16*)alloc((size_t)1024 * 1024 * 2);
    u16* wk1t = (u16*)alloc((size_t)1024 * 1024 * 2);
    u16* wv1t = (u16*)alloc((size_t)1024 * 1024 * 2);
    u16* wo1t = (u16*)alloc((size_t)1024 * 1024 * 2);
    u16* wq2t = (u16*)alloc((size_t)1024 * 1024 * 2);
    u16* wk2t = (u16*)alloc((size_t)1024 * 1024 * 2);
    u16* wv2t = (u16*)alloc((size_t)1024 * 1024 * 2);
    u16* wo2t = (u16*)alloc((size_t)1024 * 1024 * 2);
    u16* w1t = (u16*)alloc((size_t)4096 * 1024 * 2);
    u16* w2t = (u16*)alloc((size_t)1024 * 4096 * 2);
    u16* Eb  = (u16*)alloc((size_t)B_ * LE_ * D_ * 2);
    u16* XLN = (u16*)alloc(NTD * 2);
    u16* Qb  = (u16*)alloc(NTD * 2);    // Qb..KSb (67.1MB contiguous) = MLP hidden
    u16* Kb  = (u16*)alloc(NTD * 2);
    u16* Vb  = (u16*)alloc(NTD * 2);
    u16* KSb = (u16*)alloc(NTD * 2);
    u16* VSb = (u16*)alloc(NTD * 2);
    u16* Ob  = (u16*)alloc(NTD * 2);
    float* KREP = (float*)alloc((size_t)B_ * NB_ * 1024 * 4);
    float* Pm = (float*)alloc((size_t)B_ * H_ * NB_ * NB_ * 4);
    u16* HML = Qb;

    // weight transposes (once)
    transpose_k<<<dim3(32, 32), 256, 0, stream>>>(wq1, wq1t, 1024, 1024);
    transpose_k<<<dim3(32, 32), 256, 0, stream>>>(wk1, wk1t, 1024, 1024);
    transpose_k<<<dim3(32, 32), 256, 0, stream>>>(wv1, wv1t, 1024, 1024);
    transpose_k<<<dim3(32, 32), 256, 0, stream>>>(wo1, wo1t, 1024, 1024);
    transpose_k<<<dim3(32, 32), 256, 0, stream>>>(wq2, wq2t, 1024, 1024);
    transpose_k<<<dim3(32, 32), 256, 0, stream>>>(wk2, wk2t, 1024, 1024);
    transpose_k<<<dim3(32, 32), 256, 0, stream>>>(wv2, wv2t, 1024, 1024);
    transpose_k<<<dim3(32, 32), 256, 0, stream>>>(wo2, wo2t, 1024, 1024);
    transpose_k<<<dim3(128, 32), 256, 0, stream>>>(w1, w1t, 1024, 4096);
    transpose_k<<<dim3(32, 128), 256, 0, stream>>>(w2, w2t, 4096, 1024);
    conv_k<<<4096, 256, 0, stream>>>(encoded, Eb);

    ln_k<<<8192, 256, 0, stream>>>(targets, ln1s, ln1b, XLN);
    gemm_k<0, u16><<<dim3(8, 64), 256, 0, stream>>>(XLN, wq1t, nullptr, nullptr, Qb, 8192, 1024, 1024);
    gemm_k<0, u16><<<dim3(8, 64), 256, 0, stream>>>(XLN, wk1t, nullptr, nullptr, Kb, 8192, 1024, 1024);
    gemm_k<0, u16><<<dim3(8, 64), 256, 0, stream>>>(XLN, wv1t, nullptr, nullptr, Vb, 8192, 1024, 1024);
    krep_k<<<256, 256, 0, stream>>>(Kb, KREP);
    sinkhorn_k<<<64, 256, 0, stream>>>(KREP, wsort, Pm);
    sortmix_k<<<8192, 256, 0, stream>>>(Pm, Kb, Vb, KSb, VSb);
    attn_mfma_k<0><<<1024, 256, 0, stream>>>(Qb, Kb, Vb, KSb, VSb, Ob);
    gemm_k<1, float><<<dim3(8, 64), 256, 0, stream>>>(Ob, wo1t, nullptr, targets, out, 8192, 1024, 1024);
    ln_k<<<8192, 256, 0, stream>>>(out, ln2s, ln2b, XLN);
    gemm_k<0, u16><<<dim3(8, 64), 256, 0, stream>>>(XLN, wq2t, nullptr, nullptr, Qb, 8192, 1024, 1024);
    gemm_k<0, u16><<<dim3(8, 32), 256, 0, stream>>>(Eb, wk2t, nullptr, nullptr, Kb, 4096, 1024, 1024);
    gemm_k<0, u16><<<dim3(8, 32), 256, 0, stream>>>(Eb, wv2t, nullptr, nullptr, Vb, 4096, 1024, 1024);
    attn_mfma_k<1><<<1024, 256, 0, stream>>>(Qb, Kb, Vb, nullptr, nullptr, Ob);
    gemm_k<1, float><<<dim3(8, 64), 256, 0, stream>>>(Ob, wo2t, nullptr, out, out, 8192, 1024, 1024);
    ln_k<<<8192, 256, 0, stream>>>(out, ln3s, ln3b, XLN);
    gemm_k<2, u16><<<dim3(32, 64), 256, 0, stream>>>(XLN, w1t, b1, nullptr, HML, 8192, 4096, 1024);
    gemm_k<3, float><<<dim3(8, 64), 256, 0, stream>>>(HML, w2t, b2, out, out, 8192, 1024, 4096);
    return;
  }

  // ---------- per-batch fallback (proven in round 4; ~36 MB) ----------
  const size_t SLC = (size_t)LT_ * D_;
  u16* wT  = (u16*)alloc((size_t)1024 * 1024 * 2);
  u16* XLN = (u16*)alloc(SLC * 2);
  u16* Qb  = (u16*)alloc(SLC * 2);
  u16* Kb  = (u16*)alloc(SLC * 2);
  u16* Vb  = (u16*)alloc(SLC * 2);
  u16* KSb = (u16*)alloc(SLC * 2);
  u16* VSb = (u16*)alloc(SLC * 2);
  u16* Ob  = (u16*)alloc(SLC * 2);
  u16* Hc  = (u16*)alloc(SLC * 2);
  u16* Eb  = (u16*)alloc((size_t)LE_ * D_ * 2);
  float* KREP = (float*)alloc((size_t)NB_ * 1024 * 4);
  float* Pm = (float*)alloc((size_t)H_ * NB_ * NB_ * 4);

  auto T = [&](const float* src, int rs) {
    transpose_k<<<dim3(32, 32), 256, 0, stream>>>(src, wT, 1024, rs);
  };

  for (int b = 0; b < B_; ++b) {
    const float* tgt_b = targets + (size_t)b * SLC;
    const float* enc_b = encoded + (size_t)b * LE_ * D_;
    float* out_b = out + (size_t)b * SLC;

    ln_k<<<2048, 256, 0, stream>>>(tgt_b, ln1s, ln1b, XLN);
    T(wq1, 1024);
    gemm_k<0, u16><<<dim3(8, 16), 256, 0, stream>>>(XLN, wT, nullptr, nullptr, Qb, 2048, 1024, 1024);
    T(wk1, 1024);
    gemm_k<0, u16><<<dim3(8, 16), 256, 0, stream>>>(XLN, wT, nullptr, nullptr, Kb, 2048, 1024, 1024);
    T(wv1, 1024);
    gemm_k<0, u16><<<dim3(8, 16), 256, 0, stream>>>(XLN, wT, nullptr, nullptr, Vb, 2048, 1024, 1024);
    krep_k<<<64, 256, 0, stream>>>(Kb, KREP);
    sinkhorn_k<<<16, 256, 0, stream>>>(KREP, wsort, Pm);
    sortmix_k<<<2048, 256, 0, stream>>>(Pm, Kb, Vb, KSb, VSb);
    attn_mfma_k<0><<<256, 256, 0, stream>>>(Qb, Kb, Vb, KSb, VSb, Ob);
    T(wo1, 1024);
    gemm_k<1, float><<<dim3(8, 16), 256, 0, stream>>>(Ob, wT, nullptr, tgt_b, out_b, 2048, 1024, 1024);
    ln_k<<<2048, 256, 0, stream>>>(out_b, ln2s, ln2b, XLN);
    conv_k<<<1024, 256, 0, stream>>>(enc_b, Eb);
    T(wq2, 1024);
    gemm_k<0, u16><<<dim3(8, 16), 256, 0, stream>>>(XLN, wT, nullptr, nullptr, Qb, 2048, 1024, 1024);
    T(wk2, 1024);
    gemm_k<0, u16><<<dim3(8, 8), 256, 0, stream>>>(Eb, wT, nullptr, nullptr, Kb, 1024, 1024, 1024);
    T(wv2, 1024);
    gemm_k<0, u16><<<dim3(8, 8), 256, 0, stream>>>(Eb, wT, nullptr, nullptr, Vb, 1024, 1024, 1024);
    attn_mfma_k<1><<<256, 256, 0, stream>>>(Qb, Kb, Vb, nullptr, nullptr, Ob);
    T(wo2, 1024);
    gemm_k<1, float><<<dim3(8, 16), 256, 0, stream>>>(Ob, wT, nullptr, out_b, out_b, 2048, 1024, 1024);
    ln_k<<<2048, 256, 0, stream>>>(out_b, ln3s, ln3b, XLN);
    for (int c = 0; c < 4; ++c) {
      T(w1 + (size_t)c * 1024, 4096);
      gemm_k<2, u16><<<dim3(8, 16), 256, 0, stream>>>(XLN, wT, b1 + c * 1024, nullptr, Hc,
                                                      2048, 1024, 1024);
      T(w2 + (size_t)c * 1024 * 1024, 1024);
      if (c < 3)
        gemm_k<1, float><<<dim3(8, 16), 256, 0, stream>>>(Hc, wT, nullptr, out_b, out_b,
                                                          2048, 1024, 1024);
      else
        gemm_k<3, float><<<dim3(8, 16), 256, 0, stream>>>(Hc, wT, b2, out_b, out_b,
                                                          2048, 1024, 1024);
    }
  }
}

// Round 6
// 901.989 us; speedup vs baseline: 4.6365x; 1.0854x over previous
//
#include <hip/hip_runtime.h>

typedef unsigned short u16;
typedef __attribute__((ext_vector_type(8))) short short8;
typedef __attribute__((ext_vector_type(4))) short short4_t;
typedef __attribute__((ext_vector_type(4))) float float4_t;

#define B_ 4
#define LT_ 2048
#define LE_ 1024
#define D_ 1024
#define H_ 16
#define HD_ 64
#define NB_ 16
#define BS_ 128
#define M_ 4096
#define SCALE_ 0.125f

typedef __attribute__((address_space(1))) const void gas_t;
typedef __attribute__((address_space(3))) void las_t;

__device__ __forceinline__ float b2f(u16 u) {
  union { unsigned int i; float f; } v; v.i = ((unsigned int)u) << 16; return v.f;
}
__device__ __forceinline__ u16 f2b(float f) {
  union { float f; unsigned int i; } v; v.f = f;
  unsigned int x = v.i;
  return (u16)((x + 0x7fffu + ((x >> 16) & 1u)) >> 16);
}
__device__ __forceinline__ float gelu_f(float u) {
  // tanh-gelu via __expf: tanh(t) = 1 - 2/(exp(2t)+1)
  float t = 0.7978845608028654f * (u + 0.044715f * u * u * u);
  float th = 1.f - 2.f / (__expf(2.f * t) + 1.f);
  return 0.5f * u * (1.f + th);
}
__device__ __forceinline__ void store_val(u16* p, float x) { *p = f2b(x); }
__device__ __forceinline__ void store_val(float* p, float x) { *p = x; }

// ---------------- fp32 -> bf16 convert ----------------
__global__ __launch_bounds__(256)
void conv_k(const float* __restrict__ in, u16* __restrict__ out) {
  int i = (blockIdx.x * 256 + threadIdx.x) * 4;
  float4_t v = *(const float4_t*)(in + i);
  short4_t o;
  o[0] = (short)f2b(v[0]); o[1] = (short)f2b(v[1]);
  o[2] = (short)f2b(v[2]); o[3] = (short)f2b(v[3]);
  *(short4_t*)(out + i) = o;
}

// ---------------- transpose fp32 [R,Csub] (row stride) -> bf16 [Csub,R] ----------------
__global__ __launch_bounds__(256)
void transpose_k(const float* __restrict__ in, u16* __restrict__ out, int R, int rstride) {
  __shared__ u16 tile[32][33];
  int bx = blockIdx.x * 32, by = blockIdx.y * 32;
  int tx = threadIdx.x & 31, ty = threadIdx.x >> 5;
  #pragma unroll
  for (int y = ty; y < 32; y += 8)
    tile[y][tx] = f2b(in[(size_t)(by + y) * rstride + bx + tx]);
  __syncthreads();
  #pragma unroll
  for (int y = ty; y < 32; y += 8)
    out[(size_t)(bx + y) * R + by + tx] = tile[tx][y];
}

// ---------------- layernorm (rows of 1024): fp32 in -> bf16 out ----------------
__global__ __launch_bounds__(256)
void ln_k(const float* __restrict__ x, const float* __restrict__ sw,
          const float* __restrict__ bw, u16* __restrict__ out) {
  int row = blockIdx.x, tid = threadIdx.x;
  const float* xr = x + (size_t)row * 1024 + tid * 4;
  float4_t raw = *(const float4_t*)xr;
  float v0 = raw[0], v1 = raw[1], v2 = raw[2], v3 = raw[3];
  float sum = v0 + v1 + v2 + v3;
  #pragma unroll
  for (int off = 32; off > 0; off >>= 1) sum += __shfl_down(sum, off, 64);
  __shared__ float sA[4], sB[4];
  int w = tid >> 6;
  if ((tid & 63) == 0) sA[w] = sum;
  __syncthreads();
  float mu = (sA[0] + sA[1] + sA[2] + sA[3]) * (1.f / 1024.f);
  float d0 = v0 - mu, d1 = v1 - mu, d2 = v2 - mu, d3 = v3 - mu;
  float s2 = d0 * d0 + d1 * d1 + d2 * d2 + d3 * d3;
  #pragma unroll
  for (int off = 32; off > 0; off >>= 1) s2 += __shfl_down(s2, off, 64);
  if ((tid & 63) == 0) sB[w] = s2;
  __syncthreads();
  float inv = rsqrtf((sB[0] + sB[1] + sB[2] + sB[3]) * (1.f / 1024.f) + 1e-6f);
  float4_t sv = *(const float4_t*)(sw + tid * 4);
  float4_t bv = *(const float4_t*)(bw + tid * 4);
  short4_t ov;
  ov[0] = (short)f2b(d0 * inv * sv[0] + bv[0]);
  ov[1] = (short)f2b(d1 * inv * sv[1] + bv[1]);
  ov[2] = (short)f2b(d2 * inv * sv[2] + bv[2]);
  ov[3] = (short)f2b(d3 * inv * sv[3] + bv[3]);
  *(short4_t*)(out + (size_t)row * 1024 + tid * 4) = ov;
}

// ---------------- MFMA GEMM (m97 structure): C[M,N] = A[M,K] * Bt[N,K]^T ----------------
// Unpadded LDS tiles + global_load_lds width=16 (direct-to-LDS DMA). LDS dest
// is wave-uniform base + lane*16B: chunk index c = tid + u*256 -> LDS byte
// offset c*16, consecutive lanes -> consecutive 16B chunks (constraint met).
// EPI: 0=none 1=+res 2=gelu(+bias) 3=+bias+res ; res/bias fp32 ; C dtype = TC
template<int EPI, typename TC>
__global__ __launch_bounds__(256)
void gemm_k(const u16* __restrict__ A, const u16* __restrict__ Bt,
            const float* __restrict__ bias, const float* __restrict__ res,
            TC* __restrict__ C, int M, int N, int K) {
  __shared__ __align__(16) u16 lA[128 * 32];
  __shared__ __align__(16) u16 lB[128 * 32];
  const int bn = blockIdx.x * 128;
  const int bm = blockIdx.y * 128;
  const int tid = threadIdx.x;
  const int lane = tid & 63;
  const int wave = tid >> 6;
  const int wy = wave >> 1, wx = wave & 1;
  const int quad = lane >> 4, l16 = lane & 15;

  float4_t acc[4][4];
  float4_t zz = {0.f, 0.f, 0.f, 0.f};
  #pragma unroll
  for (int i = 0; i < 4; ++i)
    #pragma unroll
    for (int j = 0; j < 4; ++j) acc[i][j] = zz;

  const int r0 = tid >> 2, kc0 = (tid & 3) * 8;       // u=0 chunk
  const u16* gA0 = A + (size_t)(bm + r0) * K + kc0;
  const u16* gA1 = A + (size_t)(bm + 64 + r0) * K + kc0;
  const u16* gB0 = Bt + (size_t)(bn + r0) * K + kc0;
  const u16* gB1 = Bt + (size_t)(bn + 64 + r0) * K + kc0;
  u16* lA0 = &lA[tid * 8];
  u16* lA1 = &lA[(tid + 256) * 8];
  u16* lB0 = &lB[tid * 8];
  u16* lB1 = &lB[(tid + 256) * 8];

  for (int k0 = 0; k0 < K; k0 += 32) {
    __syncthreads();
    __builtin_amdgcn_global_load_lds((gas_t*)(gA0 + k0), (las_t*)lA0, 16, 0, 0);
    __builtin_amdgcn_global_load_lds((gas_t*)(gA1 + k0), (las_t*)lA1, 16, 0, 0);
    __builtin_amdgcn_global_load_lds((gas_t*)(gB0 + k0), (las_t*)lB0, 16, 0, 0);
    __builtin_amdgcn_global_load_lds((gas_t*)(gB1 + k0), (las_t*)lB1, 16, 0, 0);
    __syncthreads();
    short8 af[4], bfr[4];
    #pragma unroll
    for (int i = 0; i < 4; ++i)
      af[i] = *(const short8*)&lA[(wy * 64 + i * 16 + l16) * 32 + quad * 8];
    #pragma unroll
    for (int j = 0; j < 4; ++j)
      bfr[j] = *(const short8*)&lB[(wx * 64 + j * 16 + l16) * 32 + quad * 8];
    #pragma unroll
    for (int i = 0; i < 4; ++i)
      #pragma unroll
      for (int j = 0; j < 4; ++j)
        acc[i][j] = __builtin_amdgcn_mfma_f32_16x16x32_bf16(af[i], bfr[j], acc[i][j], 0, 0, 0);
  }

  #pragma unroll
  for (int i = 0; i < 4; ++i) {
    int row = bm + wy * 64 + i * 16 + quad * 4;
    #pragma unroll
    for (int j = 0; j < 4; ++j) {
      int col = bn + wx * 64 + j * 16 + l16;
      #pragma unroll
      for (int v = 0; v < 4; ++v) {
        float x = acc[i][j][v];
        size_t idx = (size_t)(row + v) * N + col;
        if (EPI == 1) {
          x += res[idx];
        } else if (EPI == 2) {
          x = gelu_f(x + bias[col]);
        } else if (EPI == 3) {
          x += bias[col] + res[idx];
        }
        store_val(&C[idx], x);
      }
    }
  }
}

// ---------------- krep: sum k over block rows (b decoded from idx) ----------------
__global__ __launch_bounds__(256)
void krep_k(const u16* __restrict__ K1, float* __restrict__ krep) {
  int idx = blockIdx.x * 256 + threadIdx.x;   // (#batches)*NB*1024
  int col = idx & 1023;
  int bn = idx >> 10;
  const u16* p = K1 + (size_t)bn * 128 * 1024 + col;
  float s = 0.f;
  for (int i = 0; i < 128; ++i) s += b2f(p[(size_t)i * 1024]);
  krep[idx] = s;
}

// ---------------- sinkhorn: grid = (#batches)*H, one (b,h) each ----------------
__global__ __launch_bounds__(256)
void sinkhorn_k(const float* __restrict__ krep, const float* __restrict__ wsort,
                float* __restrict__ P) {
  int bh = blockIdx.x;
  int b = bh >> 4, h = bh & 15;
  int t = threadIdx.x;
  int i = t >> 4, j = t & 15;
  __shared__ float la[16][17];
  __shared__ float red[16];
  float acc = 0.f;
  const float* kr = krep + ((size_t)b * 16 + i) * 1024 + h * 64;
  const float* ws = wsort + (size_t)h * 64 * 16 + j;
  for (int k = 0; k < 64; ++k) acc += kr[k] * ws[k * 16];
  la[i][j] = (j <= i) ? acc : -1e9f;
  __syncthreads();
  for (int it = 0; it < 5; ++it) {
    if (t < 16) {
      float m = -1e30f;
      for (int jj = 0; jj < 16; ++jj) m = fmaxf(m, la[t][jj]);
      float s = 0.f;
      for (int jj = 0; jj < 16; ++jj) s += __expf(la[t][jj] - m);
      red[t] = m + __logf(s);
    }
    __syncthreads();
    la[i][j] = (j <= i) ? la[i][j] - red[i] : -1e9f;
    __syncthreads();
    if (t < 16) {
      float m = -1e30f;
      for (int ii = 0; ii < 16; ++ii) m = fmaxf(m, la[ii][t]);
      float s = 0.f;
      for (int ii = 0; ii < 16; ++ii) s += __expf(la[ii][t] - m);
      red[t] = m + __logf(s);
    }
    __syncthreads();
    la[i][j] = (j <= i) ? la[i][j] - red[j] : -1e9f;
    __syncthreads();
  }
  P[((size_t)bh * 16 + i) * 16 + j] = __expf(la[i][j]);
}

// ---------------- sorted block mix (b decoded from idx) ----------------
__global__ __launch_bounds__(256)
void sortmix_k(const float* __restrict__ P, const u16* __restrict__ K1,
               const u16* __restrict__ V1, u16* __restrict__ KS,
               u16* __restrict__ VS) {
  int t = blockIdx.x * 256 + threadIdx.x;     // (#batches)*2048*256 (4 cols each)
  int col = (t & 255) * 4;
  int rest = t >> 8;                          // b*2048 + i*128 + s
  int b = rest >> 11, is = rest & 2047, i = is >> 7, s = is & 127;
  int h = col >> 6;
  const float* Pr = P + (((size_t)(b * 16 + h)) * 16 + i) * 16;
  size_t base = ((size_t)(b * 2048 + s)) * 1024 + col;
  float ka[4] = {0, 0, 0, 0}, va[4] = {0, 0, 0, 0};
  for (int j = 0; j <= i; ++j) {   // P[i][j]==0 for j>i (causal mask)
    float p = Pr[j];
    short4_t kk = *(const short4_t*)&K1[base + (size_t)j * 131072];
    short4_t vv = *(const short4_t*)&V1[base + (size_t)j * 131072];
    #pragma unroll
    for (int e = 0; e < 4; ++e) {
      ka[e] += p * b2f((u16)kk[e]);
      va[e] += p * b2f((u16)vv[e]);
    }
  }
  size_t ob = ((size_t)(b * 2048 + i * 128 + s)) * 1024 + col;
  short4_t ok, ov;
  #pragma unroll
  for (int e = 0; e < 4; ++e) { ok[e] = (short)f2b(ka[e]); ov[e] = (short)f2b(va[e]); }
  *(short4_t*)&KS[ob] = ok;
  *(short4_t*)&VS[ob] = ov;
}

// ---------------- MFMA flash attention ----------------
#define KLS 72
#define VTS 136
#define PLS 136

template<int CROSS>
__global__ __launch_bounds__(256)
void attn_mfma_k(const u16* __restrict__ Q, const u16* __restrict__ Ka,
                 const u16* __restrict__ Va, const u16* __restrict__ Kb2,
                 const u16* __restrict__ Vb2, u16* __restrict__ O) {
  __shared__ __align__(16) u16 kls[128 * KLS];
  __shared__ __align__(16) u16 vtls[64 * VTS];
  __shared__ __align__(16) u16 pls[128 * PLS];
  const int blk = blockIdx.x;
  const int n = blk & 15, h = (blk >> 4) & 15, b = blk >> 8;
  const int tid = threadIdx.x, lane = tid & 63, wv = tid >> 6;
  const int quad = lane >> 4, l16 = lane & 15;
  const int m0 = wv * 32;
  const size_t qrowbase = (size_t)b * 2048 + n * 128;

  short8 qa[2][2];
  #pragma unroll
  for (int mi = 0; mi < 2; ++mi)
    #pragma unroll
    for (int ks = 0; ks < 2; ++ks)
      qa[mi][ks] = *(const short8*)&Q[(qrowbase + m0 + mi * 16 + l16) * 1024 +
                                      h * 64 + ks * 32 + quad * 8];

  float4_t acc_o[2][4];
  float mrow[2][4], lrow[2][4];
  #pragma unroll
  for (int mi = 0; mi < 2; ++mi)
    #pragma unroll
    for (int dn = 0; dn < 4; ++dn) acc_o[mi][dn] = {0.f, 0.f, 0.f, 0.f};
  #pragma unroll
  for (int mi = 0; mi < 2; ++mi)
    #pragma unroll
    for (int v = 0; v < 4; ++v) { mrow[mi][v] = -1e30f; lrow[mi][v] = 0.f; }

  const int NT = CROSS ? 8 : 2;
  for (int t = 0; t < NT; ++t) {
    const u16 *Kg, *Vg;
    bool causal = false;
    if (CROSS) {
      size_t kb = ((size_t)b * 1024 + t * 128) * 1024 + h * 64;
      Kg = Ka + kb; Vg = Va + kb;
    } else if (t == 0) {
      size_t kb = qrowbase * 1024 + h * 64;
      Kg = Ka + kb; Vg = Va + kb; causal = true;
    } else {
      size_t kb = qrowbase * 1024 + h * 64;
      Kg = Kb2 + kb; Vg = Vb2 + kb;
    }
    __syncthreads();                   // prior tile's LDS readers done
    #pragma unroll
    for (int i = 0; i < 4; ++i) {
      int c = tid + i * 256;
      int row = c >> 3, dd = (c & 7) * 8;
      short8 kv = *(const short8*)&Kg[(size_t)row * 1024 + dd];
      *(short8*)&kls[row * KLS + dd] = kv;
      short8 vv = *(const short8*)&Vg[(size_t)row * 1024 + dd];
      #pragma unroll
      for (int e = 0; e < 8; ++e) vtls[(dd + e) * VTS + row] = (u16)vv[e];
    }
    __syncthreads();

    float4_t s[2][8];
    #pragma unroll
    for (int mi = 0; mi < 2; ++mi)
      #pragma unroll
      for (int nj = 0; nj < 8; ++nj) s[mi][nj] = {0.f, 0.f, 0.f, 0.f};
    #pragma unroll
    for (int nj = 0; nj < 8; ++nj) {
      short8 b0 = *(const short8*)&kls[(nj * 16 + l16) * KLS + quad * 8];
      short8 b1 = *(const short8*)&kls[(nj * 16 + l16) * KLS + 32 + quad * 8];
      #pragma unroll
      for (int mi = 0; mi < 2; ++mi) {
        s[mi][nj] = __builtin_amdgcn_mfma_f32_16x16x32_bf16(qa[mi][0], b0, s[mi][nj], 0, 0, 0);
        s[mi][nj] = __builtin_amdgcn_mfma_f32_16x16x32_bf16(qa[mi][1], b1, s[mi][nj], 0, 0, 0);
      }
    }
    #pragma unroll
    for (int mi = 0; mi < 2; ++mi) {
      #pragma unroll
      for (int v = 0; v < 4; ++v) {
        int rowl = m0 + mi * 16 + quad * 4 + v;
        float mx = -1e30f;
        #pragma unroll
        for (int nj = 0; nj < 8; ++nj) {
          float x = s[mi][nj][v] * SCALE_;
          if (causal && (nj * 16 + l16 > rowl)) x = -1e30f;
          s[mi][nj][v] = x;
          mx = fmaxf(mx, x);
        }
        #pragma unroll
        for (int off = 1; off < 16; off <<= 1) mx = fmaxf(mx, __shfl_xor(mx, off, 64));
        float mn = fmaxf(mrow[mi][v], mx);
        float cr = __expf(mrow[mi][v] - mn);
        mrow[mi][v] = mn;
        float rs = 0.f;
        #pragma unroll
        for (int nj = 0; nj < 8; ++nj) {
          float p = __expf(s[mi][nj][v] - mn);
          s[mi][nj][v] = p;
          rs += p;
        }
        #pragma unroll
        for (int off = 1; off < 16; off <<= 1) rs += __shfl_xor(rs, off, 64);
        lrow[mi][v] = lrow[mi][v] * cr + rs;
        #pragma unroll
        for (int dn = 0; dn < 4; ++dn) acc_o[mi][dn][v] *= cr;
        #pragma unroll
        for (int nj = 0; nj < 8; ++nj)
          pls[rowl * PLS + nj * 16 + l16] = f2b(s[mi][nj][v]);
      }
    }
    #pragma unroll
    for (int ks = 0; ks < 4; ++ks) {
      short8 a0 = *(const short8*)&pls[(m0 + l16) * PLS + ks * 32 + quad * 8];
      short8 a1 = *(const short8*)&pls[(m0 + 16 + l16) * PLS + ks * 32 + quad * 8];
      #pragma unroll
      for (int dn = 0; dn < 4; ++dn) {
        short8 bv = *(const short8*)&vtls[(dn * 16 + l16) * VTS + ks * 32 + quad * 8];
        acc_o[0][dn] = __builtin_amdgcn_mfma_f32_16x16x32_bf16(a0, bv, acc_o[0][dn], 0, 0, 0);
        acc_o[1][dn] = __builtin_amdgcn_mfma_f32_16x16x32_bf16(a1, bv, acc_o[1][dn], 0, 0, 0);
      }
    }
  }
  #pragma unroll
  for (int mi = 0; mi < 2; ++mi)
    #pragma unroll
    for (int v = 0; v < 4; ++v) {
      int rowl = m0 + mi * 16 + quad * 4 + v;
      float inv = 1.f / lrow[mi][v];
      #pragma unroll
      for (int dn = 0; dn < 4; ++dn)
        O[(qrowbase + rowl) * 1024 + h * 64 + dn * 16 + l16] =
            f2b(acc_o[mi][dn][v] * inv);
    }
}

// ---------------- host ----------------
extern "C" void kernel_launch(void* const* d_in, const int* in_sizes, int n_in,
                              void* d_out, int out_size, void* d_ws, size_t ws_size,
                              hipStream_t stream) {
  const float* targets = (const float*)d_in[0];
  const float* encoded = (const float*)d_in[1];
  const float* ln1s = (const float*)d_in[2];
  const float* ln1b = (const float*)d_in[3];
  const float* ln2s = (const float*)d_in[4];
  const float* ln2b = (const float*)d_in[5];
  const float* ln3s = (const float*)d_in[6];
  const float* ln3b = (const float*)d_in[7];
  const float* wq1 = (const float*)d_in[8];
  const float* wk1 = (const float*)d_in[9];
  const float* wv1 = (const float*)d_in[10];
  const float* wo1 = (const float*)d_in[11];
  const float* wsort = (const float*)d_in[12];
  const float* wq2 = (const float*)d_in[13];
  const float* wk2 = (const float*)d_in[14];
  const float* wv2 = (const float*)d_in[15];
  const float* wo2 = (const float*)d_in[16];
  const float* w1 = (const float*)d_in[17];
  const float* b1 = (const float*)d_in[18];
  const float* w2 = (const float*)d_in[19];
  const float* b2 = (const float*)d_in[20];
  float* out = (float*)d_out;
  (void)in_sizes; (void)n_in; (void)out_size;

  char* ws = (char*)d_ws;
  size_t off = 0;
  auto alloc = [&](size_t n) -> char* {
    char* p = ws + off;
    off += (n + 255) & ~(size_t)255;
    return p;
  };

  const size_t NTD = (size_t)B_ * LT_ * D_;         // 8.4M elems
  const size_t NEED_BIG = (size_t)(8 * 2 + 8 + 8) * 1024 * 1024   // weights bf16
                        + (size_t)LE_ * B_ * D_ * 2                // Eb
                        + NTD * 2 * 7                              // XLN + 6 act
                        + (1u << 20);                              // small + slack

  if (ws_size >= NEED_BIG) {
    // ---------- whole-batch path ----------
    u16* wq1t = (u16*)alloc((size_t)1024 * 1024 * 2);
    u16* wk1t = (u16*)alloc((size_t)1024 * 1024 * 2);
    u16* wv1t = (u16*)alloc((size_t)1024 * 1024 * 2);
    u16* wo1t = (u16*)alloc((size_t)1024 * 1024 * 2);
    u16* wq2t = (u16*)alloc((size_t)1024 * 1024 * 2);
    u16* wk2t = (u16*)alloc((size_t)1024 * 1024 * 2);
    u16* wv2t = (u16*)alloc((size_t)1024 * 1024 * 2);
    u16* wo2t = (u16*)alloc((size_t)1024 * 1024 * 2);
    u16* w1t = (u16*)alloc((size_t)4096 * 1024 * 2);
    u16* w2t = (u16*)alloc((size_t)1024 * 4096 * 2);
    u16* Eb  = (u16*)alloc((size_t)B_ * LE_ * D_ * 2);
    u16* XLN = (u16*)alloc(NTD * 2);
    u16* Qb  = (u16*)alloc(NTD * 2);    // Qb..KSb (67.1MB contiguous) = MLP hidden
    u16* Kb  = (u16*)alloc(NTD * 2);
    u16* Vb  = (u16*)alloc(NTD * 2);
    u16* KSb = (u16*)alloc(NTD * 2);
    u16* VSb = (u16*)alloc(NTD * 2);
    u16* Ob  = (u16*)alloc(NTD * 2);
    float* KREP = (float*)alloc((size_t)B_ * NB_ * 1024 * 4);
    float* Pm = (float*)alloc((size_t)B_ * H_ * NB_ * NB_ * 4);
    u16* HML = Qb;

    transpose_k<<<dim3(32, 32), 256, 0, stream>>>(wq1, wq1t, 1024, 1024);
    transpose_k<<<dim3(32, 32), 256, 0, stream>>>(wk1, wk1t, 1024, 1024);
    transpose_k<<<dim3(32, 32), 256, 0, stream>>>(wv1, wv1t, 1024, 1024);
    transpose_k<<<dim3(32, 32), 256, 0, stream>>>(wo1, wo1t, 1024, 1024);
    transpose_k<<<dim3(32, 32), 256, 0, stream>>>(wq2, wq2t, 1024, 1024);
    transpose_k<<<dim3(32, 32), 256, 0, stream>>>(wk2, wk2t, 1024, 1024);
    transpose_k<<<dim3(32, 32), 256, 0, stream>>>(wv2, wv2t, 1024, 1024);
    transpose_k<<<dim3(32, 32), 256, 0, stream>>>(wo2, wo2t, 1024, 1024);
    transpose_k<<<dim3(128, 32), 256, 0, stream>>>(w1, w1t, 1024, 4096);
    transpose_k<<<dim3(32, 128), 256, 0, stream>>>(w2, w2t, 4096, 1024);
    conv_k<<<4096, 256, 0, stream>>>(encoded, Eb);

    ln_k<<<8192, 256, 0, stream>>>(targets, ln1s, ln1b, XLN);
    gemm_k<0, u16><<<dim3(8, 64), 256, 0, stream>>>(XLN, wq1t, nullptr, nullptr, Qb, 8192, 1024, 1024);
    gemm_k<0, u16><<<dim3(8, 64), 256, 0, stream>>>(XLN, wk1t, nullptr, nullptr, Kb, 8192, 1024, 1024);
    gemm_k<0, u16><<<dim3(8, 64), 256, 0, stream>>>(XLN, wv1t, nullptr, nullptr, Vb, 8192, 1024, 1024);
    krep_k<<<256, 256, 0, stream>>>(Kb, KREP);
    sinkhorn_k<<<64, 256, 0, stream>>>(KREP, wsort, Pm);
    sortmix_k<<<8192, 256, 0, stream>>>(Pm, Kb, Vb, KSb, VSb);
    attn_mfma_k<0><<<1024, 256, 0, stream>>>(Qb, Kb, Vb, KSb, VSb, Ob);
    gemm_k<1, float><<<dim3(8, 64), 256, 0, stream>>>(Ob, wo1t, nullptr, targets, out, 8192, 1024, 1024);
    ln_k<<<8192, 256, 0, stream>>>(out, ln2s, ln2b, XLN);
    gemm_k<0, u16><<<dim3(8, 64), 256, 0, stream>>>(XLN, wq2t, nullptr, nullptr, Qb, 8192, 1024, 1024);
    gemm_k<0, u16><<<dim3(8, 32), 256, 0, stream>>>(Eb, wk2t, nullptr, nullptr, Kb, 4096, 1024, 1024);
    gemm_k<0, u16><<<dim3(8, 32), 256, 0, stream>>>(Eb, wv2t, nullptr, nullptr, Vb, 4096, 1024, 1024);
    attn_mfma_k<1><<<1024, 256, 0, stream>>>(Qb, Kb, Vb, nullptr, nullptr, Ob);
    gemm_k<1, float><<<dim3(8, 64), 256, 0, stream>>>(Ob, wo2t, nullptr, out, out, 8192, 1024, 1024);
    ln_k<<<8192, 256, 0, stream>>>(out, ln3s, ln3b, XLN);
    gemm_k<2, u16><<<dim3(32, 64), 256, 0, stream>>>(XLN, w1t, b1, nullptr, HML, 8192, 4096, 1024);
    gemm_k<3, float><<<dim3(8, 64), 256, 0, stream>>>(HML, w2t, b2, out, out, 8192, 1024, 4096);
    return;
  }

  // ---------- per-batch fallback (~36 MB) ----------
  const size_t SLC = (size_t)LT_ * D_;
  u16* wT  = (u16*)alloc((size_t)1024 * 1024 * 2);
  u16* XLN = (u16*)alloc(SLC * 2);
  u16* Qb  = (u16*)alloc(SLC * 2);
  u16* Kb  = (u16*)alloc(SLC * 2);
  u16* Vb  = (u16*)alloc(SLC * 2);
  u16* KSb = (u16*)alloc(SLC * 2);
  u16* VSb = (u16*)alloc(SLC * 2);
  u16* Ob  = (u16*)alloc(SLC * 2);
  u16* Hc  = (u16*)alloc(SLC * 2);
  u16* Eb  = (u16*)alloc((size_t)LE_ * D_ * 2);
  float* KREP = (float*)alloc((size_t)NB_ * 1024 * 4);
  float* Pm = (float*)alloc((size_t)H_ * NB_ * NB_ * 4);

  auto T = [&](const float* src, int rs) {
    transpose_k<<<dim3(32, 32), 256, 0, stream>>>(src, wT, 1024, rs);
  };

  for (int b = 0; b < B_; ++b) {
    const float* tgt_b = targets + (size_t)b * SLC;
    const float* enc_b = encoded + (size_t)b * LE_ * D_;
    float* out_b = out + (size_t)b * SLC;

    ln_k<<<2048, 256, 0, stream>>>(tgt_b, ln1s, ln1b, XLN);
    T(wq1, 1024);
    gemm_k<0, u16><<<dim3(8, 16), 256, 0, stream>>>(XLN, wT, nullptr, nullptr, Qb, 2048, 1024, 1024);
    T(wk1, 1024);
    gemm_k<0, u16><<<dim3(8, 16), 256, 0, stream>>>(XLN, wT, nullptr, nullptr, Kb, 2048, 1024, 1024);
    T(wv1, 1024);
    gemm_k<0, u16><<<dim3(8, 16), 256, 0, stream>>>(XLN, wT, nullptr, nullptr, Vb, 2048, 1024, 1024);
    krep_k<<<64, 256, 0, stream>>>(Kb, KREP);
    sinkhorn_k<<<16, 256, 0, stream>>>(KREP, wsort, Pm);
    sortmix_k<<<2048, 256, 0, stream>>>(Pm, Kb, Vb, KSb, VSb);
    attn_mfma_k<0><<<256, 256, 0, stream>>>(Qb, Kb, Vb, KSb, VSb, Ob);
    T(wo1, 1024);
    gemm_k<1, float><<<dim3(8, 16), 256, 0, stream>>>(Ob, wT, nullptr, tgt_b, out_b, 2048, 1024, 1024);
    ln_k<<<2048, 256, 0, stream>>>(out_b, ln2s, ln2b, XLN);
    conv_k<<<1024, 256, 0, stream>>>(enc_b, Eb);
    T(wq2, 1024);
    gemm_k<0, u16><<<dim3(8, 16), 256, 0, stream>>>(XLN, wT, nullptr, nullptr, Qb, 2048, 1024, 1024);
    T(wk2, 1024);
    gemm_k<0, u16><<<dim3(8, 8), 256, 0, stream>>>(Eb, wT, nullptr, nullptr, Kb, 1024, 1024, 1024);
    T(wv2, 1024);
    gemm_k<0, u16><<<dim3(8, 8), 256, 0, stream>>>(Eb, wT, nullptr, nullptr, Vb, 1024, 1024, 1024);
    attn_mfma_k<1><<<256, 256, 0, stream>>>(Qb, Kb, Vb, nullptr, nullptr, Ob);
    T(wo2, 1024);
    gemm_k<1, float><<<dim3(8, 16), 256, 0, stream>>>(Ob, wT, nullptr, out_b, out_b, 2048, 1024, 1024);
    ln_k<<<2048, 256, 0, stream>>>(out_b, ln3s, ln3b, XLN);
    for (int c = 0; c < 4; ++c) {
      T(w1 + (size_t)c * 1024, 4096);
      gemm_k<2, u16><<<dim3(8, 16), 256, 0, stream>>>(XLN, wT, b1 + c * 1024, nullptr, Hc,
                                                      2048, 1024, 1024);
      T(w2 + (size_t)c * 1024 * 1024, 1024);
      if (c < 3)
        gemm_k<1, float><<<dim3(8, 16), 256, 0, stream>>>(Hc, wT, nullptr, out_b, out_b,
                                                          2048, 1024, 1024);
      else
        gemm_k<3, float><<<dim3(8, 16), 256, 0, stream>>>(Hc, wT, b2, out_b, out_b,
                                                          2048, 1024, 1024);
    }
  }
}